// Round 3
// baseline (533.252 us; speedup 1.0000x reference)
//
#include <hip/hip_runtime.h>

#define NN 100000
#define NE 1600000
#define F  32

// ---- init: linked-list heads = -1, gsum = 0 (idempotent, no memset dependence) ----
__global__ void init_kernel(int* __restrict__ head_out, int* __restrict__ head_in,
                            float* __restrict__ gsum) {
    int i = blockIdx.x * blockDim.x + threadIdx.x;
    if (i < NN) { head_out[i] = -1; head_in[i] = -1; }
    if (i == 0) gsum[0] = 0.f;
}

// ---- build per-node edge linked lists (by src and by dst) ----
__global__ void build_kernel(const int* __restrict__ src, const int* __restrict__ dst,
                             int* __restrict__ head_out, int* __restrict__ head_in,
                             int* __restrict__ next_out, int* __restrict__ next_in) {
    int e = blockIdx.x * blockDim.x + threadIdx.x;
    if (e >= NE) return;
    next_out[e] = atomicExch(&head_out[src[e]], e);
    next_in[e]  = atomicExch(&head_in[dst[e]],  e);
}

// ---- fused: gather diffusion + gates + output reduction (1 thread / node) ----
// H = 0 initially => gates only see the first 32 rows (c<32) of each 64x32 W slice,
// R-gate is dead (H*R = 0), and H_new = (1-sigmoid(gz)) * tanh(gh).
// To[i] = sum_{e:src=i} w_e x[dst_e] / deg_out[i];  Ti[i] = sum_{e:dst=i} w_e x[src_e] / deg_in[i]
// gz = x@(Wz[0,0]+Wz[1,0]) + To@Wz[0,1] + Ti@Wz[1,1] + bz ; gh likewise with Wh.
// s = relu(H_new) . Wlin summed over nodes into gsum.
__global__ __launch_bounds__(256) void RecurrentGCN_69587060130083_kernel(
    const float* __restrict__ x,
    const float* __restrict__ ew,
    const int* __restrict__ src, const int* __restrict__ dst,
    const int* __restrict__ head_out, const int* __restrict__ head_in,
    const int* __restrict__ next_out, const int* __restrict__ next_in,
    const float* __restrict__ Wz, const float* __restrict__ bz,
    const float* __restrict__ Wh, const float* __restrict__ bh,
    const float* __restrict__ Wl,
    float* __restrict__ gsum)
{
    // transposed [f][c] so the c-inner loop reads contiguous LDS (uniform addr = broadcast)
    __shared__ float sWz0[1024], sWzo[1024], sWzi[1024];
    __shared__ float sWh0[1024], sWho[1024], sWhi[1024];
    __shared__ float sbz[32], sbh[32], swl[32];
    __shared__ float wsum[4];
    int tid = threadIdx.x;

    for (int idx = tid; idx < 1024; idx += 256) {
        int c = idx >> 5, f = idx & 31;
        int tr = f * 32 + c;
        // W[dir,k,c,f] flat = dir*4096 + k*2048 + c*32 + f ; only c<32 matters (H=0)
        sWz0[tr] = Wz[idx] + Wz[4096 + idx];
        sWzo[tr] = Wz[2048 + idx];
        sWzi[tr] = Wz[6144 + idx];
        sWh0[tr] = Wh[idx] + Wh[4096 + idx];
        sWho[tr] = Wh[2048 + idx];
        sWhi[tr] = Wh[6144 + idx];
    }
    if (tid < 32) {
        sbz[tid] = bz[tid];
        sbh[tid] = bh[tid];
        swl[tid] = Wl[tid];
    }
    __syncthreads();

    int i = blockIdx.x * 256 + tid;
    float s_acc = 0.f;
    if (i < NN) {
        float xv[F], tov[F], tiv[F];
#pragma unroll
        for (int c = 0; c < F; c++) { tov[c] = 0.f; tiv[c] = 0.f; }

        const float4* xr = (const float4*)(x + (size_t)i * F);
#pragma unroll
        for (int j = 0; j < 8; j++) {
            float4 p = xr[j];
            xv[4*j+0] = p.x; xv[4*j+1] = p.y; xv[4*j+2] = p.z; xv[4*j+3] = p.w;
        }

        // out-direction gather: edges with src == i
        float deg_o = 0.f;
        for (int e = head_out[i]; e >= 0; e = next_out[e]) {
            float w = ew[e];
            deg_o += w;
            const float4* nr = (const float4*)(x + (size_t)dst[e] * F);
#pragma unroll
            for (int j = 0; j < 8; j++) {
                float4 p = nr[j];
                tov[4*j+0] += w * p.x; tov[4*j+1] += w * p.y;
                tov[4*j+2] += w * p.z; tov[4*j+3] += w * p.w;
            }
        }
        // in-direction gather: edges with dst == i
        float deg_i = 0.f;
        for (int e = head_in[i]; e >= 0; e = next_in[e]) {
            float w = ew[e];
            deg_i += w;
            const float4* nr = (const float4*)(x + (size_t)src[e] * F);
#pragma unroll
            for (int j = 0; j < 8; j++) {
                float4 p = nr[j];
                tiv[4*j+0] += w * p.x; tiv[4*j+1] += w * p.y;
                tiv[4*j+2] += w * p.z; tiv[4*j+3] += w * p.w;
            }
        }
        float dio = 1.f / deg_o, dii = 1.f / deg_i;
#pragma unroll
        for (int c = 0; c < F; c++) { tov[c] *= dio; tiv[c] *= dii; }

#pragma unroll 4
        for (int f = 0; f < 32; f++) {
            float gz = sbz[f], gh = sbh[f];
            const float* wz0 = &sWz0[f * 32];
            const float* wzo = &sWzo[f * 32];
            const float* wzi = &sWzi[f * 32];
            const float* wh0 = &sWh0[f * 32];
            const float* who = &sWho[f * 32];
            const float* whi = &sWhi[f * 32];
#pragma unroll
            for (int c = 0; c < 32; c++) {
                gz += xv[c] * wz0[c] + tov[c] * wzo[c] + tiv[c] * wzi[c];
                gh += xv[c] * wh0[c] + tov[c] * who[c] + tiv[c] * whi[c];
            }
            float Z  = 1.f / (1.f + __expf(-gz));
            float Ht = tanhf(gh);
            float hv = (1.f - Z) * Ht;
            hv = hv > 0.f ? hv : 0.f;
            s_acc += hv * swl[f];
        }
    }
    // wave64 reduce -> cross-wave via LDS -> one atomic per block
#pragma unroll
    for (int off = 32; off > 0; off >>= 1) s_acc += __shfl_down(s_acc, off);
    if ((tid & 63) == 0) wsum[tid >> 6] = s_acc;
    __syncthreads();
    if (tid == 0) atomicAdd(gsum, wsum[0] + wsum[1] + wsum[2] + wsum[3]);
}

__global__ void finalize_kernel(const float* __restrict__ gsum,
                                const float* __restrict__ blin,
                                float* __restrict__ out) {
    out[0] = gsum[0] / (float)NN + blin[0];
}

extern "C" void kernel_launch(void* const* d_in, const int* in_sizes, int n_in,
                              void* d_out, int out_size, void* d_ws, size_t ws_size,
                              hipStream_t stream) {
    // ALL float inputs are fp32 (reference uses jax float32 defaults); output fp32.
    const float* x  = (const float*)d_in[0];
    const float* ew = (const float*)d_in[1];
    const float* Wz = (const float*)d_in[2];
    const float* bz = (const float*)d_in[3];
    // d_in[4], d_in[5] = W_r, b_r: dead (H=0 => H*R=0 => R never used)
    const float* Wh = (const float*)d_in[6];
    const float* bh = (const float*)d_in[7];
    const float* Wl = (const float*)d_in[8];
    const float* bl = (const float*)d_in[9];
    const int* ei  = (const int*)d_in[10];
    const int* src = ei;
    const int* dst = ei + NE;

    // ws words: head_out[N] | head_in[N] | next_out[E] | next_in[E] | gsum  (13.6 MB)
    int* iws = (int*)d_ws;
    int* head_out = iws;
    int* head_in  = iws + NN;
    int* next_out = iws + 2 * NN;
    int* next_in  = iws + 2 * NN + NE;
    float* gsum   = (float*)(iws + 2 * NN + 2 * NE);

    init_kernel<<<(NN + 255) / 256, 256, 0, stream>>>(head_out, head_in, gsum);
    build_kernel<<<(NE + 255) / 256, 256, 0, stream>>>(src, dst, head_out, head_in,
                                                       next_out, next_in);
    RecurrentGCN_69587060130083_kernel<<<(NN + 255) / 256, 256, 0, stream>>>(
        x, ew, src, dst, head_out, head_in, next_out, next_in,
        Wz, bz, Wh, bh, Wl, gsum);
    finalize_kernel<<<1, 1, 0, stream>>>(gsum, bl, (float*)d_out);
}